// Round 1
// baseline (517.573 us; speedup 1.0000x reference)
//
#include <hip/hip_runtime.h>
#include <hip/hip_bf16.h>
#include <math.h>

// SCSA: x(32,512,64,64) fp32 -> 256 "images" of 64ch x 64 x 64 (G=8).
//   ch 0-31 : channel attention  x * sigmoid(cw*gap + cb)
//   ch 32-63: spatial attention  x * sigmoid(a_h[h]*a_w[w]*x_s)
// where a_h/a_w come from 32x32 convs over GN(h-swish'd) pooled features.
// Output = channel-shuffled concat.

#define HW 4096      // 64*64
#define CG 32        // channels per half-group
#define NBG 256      // 32 batches * 8 groups

__device__ __forceinline__ float sigmoidf_(float t) {
    return 1.0f / (1.0f + __expf(-t));
}

// ---------------------------------------------------------------------------
// Kernel 1: per-(image,channel) plane reductions. One wave (64 lanes)/block.
// Produces: s_c[bg][32]  (channel-attention sigmoid scale, ch<32)
//           x_s[bg][32]  (global mean, ch>=32)
//           x_h[bg][32][64] (row means = mean over w)
//           x_w[bg][32][64] (col means = mean over h)
// ---------------------------------------------------------------------------
__global__ __launch_bounds__(64) void k_reduce(
    const float* __restrict__ x,
    const float* __restrict__ cweight, const float* __restrict__ cbias,
    float* __restrict__ s_c, float* __restrict__ x_s,
    float* __restrict__ x_h, float* __restrict__ x_w) {
    int bid = blockIdx.x;            // 0..16383
    int bg  = bid >> 6;              // image 0..255
    int ch  = bid & 63;              // channel in image
    int b = bg >> 3, g = bg & 7;
    const float4* plane = (const float4*)(x + (size_t)(b * 512 + g * 64 + ch) * HW);
    int l = threadIdx.x;             // lane 0..63

    __shared__ float rowsum[64];

    // iter i, lane l -> float4 covering row (4i + l/16), cols 4*(l&15)..+3
    float cs0 = 0.f, cs1 = 0.f, cs2 = 0.f, cs3 = 0.f;
#pragma unroll
    for (int i = 0; i < 16; ++i) {
        float4 v = plane[i * 64 + l];
        cs0 += v.x; cs1 += v.y; cs2 += v.z; cs3 += v.w;
        float rs = (v.x + v.y) + (v.z + v.w);
        rs += __shfl_xor(rs, 1);
        rs += __shfl_xor(rs, 2);
        rs += __shfl_xor(rs, 4);
        rs += __shfl_xor(rs, 8);          // full row sum in all 16 lanes of subgroup
        if ((l & 15) == 0) rowsum[i * 4 + (l >> 4)] = rs;
    }
    // column sums: combine lanes {l, l^16, l^32, l^48} (same cols, different rows)
    cs0 += __shfl_xor(cs0, 16); cs0 += __shfl_xor(cs0, 32);
    cs1 += __shfl_xor(cs1, 16); cs1 += __shfl_xor(cs1, 32);
    cs2 += __shfl_xor(cs2, 16); cs2 += __shfl_xor(cs2, 32);
    cs3 += __shfl_xor(cs3, 16); cs3 += __shfl_xor(cs3, 32);
    float tot = (cs0 + cs1) + (cs2 + cs3);
    tot += __shfl_xor(tot, 1);
    tot += __shfl_xor(tot, 2);
    tot += __shfl_xor(tot, 4);
    tot += __shfl_xor(tot, 8);            // total plane sum in every lane

    __syncthreads();                       // rowsum visible

    if (ch < CG) {
        if (l == 0) {
            float gap = tot * (1.0f / HW);
            float t = cweight[ch] * gap + cbias[ch];
            s_c[bg * CG + ch] = sigmoidf_(t);
        }
    } else {
        int c1 = ch - CG;
        if (l == 0) x_s[bg * CG + c1] = tot * (1.0f / HW);
        if (l < 16) {
            float4 cw;
            cw.x = cs0 * (1.0f / 64.0f); cw.y = cs1 * (1.0f / 64.0f);
            cw.z = cs2 * (1.0f / 64.0f); cw.w = cs3 * (1.0f / 64.0f);
            ((float4*)(x_w + (size_t)(bg * CG + c1) * 64))[l] = cw;
        }
        x_h[(size_t)(bg * CG + c1) * 64 + l] = rowsum[l] * (1.0f / 64.0f);
    }
}

// ---------------------------------------------------------------------------
// Kernel 2: per-image conv1 -> GN -> h-swish -> convh/convw. 256 blocks x 128.
// Thread t == position p in the 128-long pooled sequence (0-63: h, 64-127: w).
// Produces a_h[bg][32][64] and a_ws[bg][32][64] (= a_w * x_s premultiplied).
// ---------------------------------------------------------------------------
__global__ __launch_bounds__(128) void k_mid(
    const float* __restrict__ x_h, const float* __restrict__ x_w,
    const float* __restrict__ x_s,
    const float* __restrict__ w1, const float* __restrict__ b1,
    const float* __restrict__ gn_g, const float* __restrict__ gn_b,
    const float* __restrict__ wh, const float* __restrict__ bh,
    const float* __restrict__ ww, const float* __restrict__ bw,
    float* __restrict__ a_h, float* __restrict__ a_ws) {
    int bg = blockIdx.x;
    int t  = threadIdx.x;

    __shared__ float sv[32][129];     // pooled features (pad 129: conflict-free both ways)
    __shared__ float sy[32][129];     // conv1 output
    __shared__ float sw1[32][32], swh[32][32], sww[32][32];
    __shared__ float sb1[32], sbh[32], sbw[32], sgg[32], sgb[32], sxs[32];
    __shared__ float spart[2][4][32];
    __shared__ float sscale[32], sshift[32];

    for (int idx = t; idx < 1024; idx += 128) {
        (&sw1[0][0])[idx] = w1[idx];
        (&swh[0][0])[idx] = wh[idx];
        (&sww[0][0])[idx] = ww[idx];
    }
    if (t < 32) {
        sb1[t] = b1[t]; sbh[t] = bh[t]; sbw[t] = bw[t];
        sgg[t] = gn_g[t]; sgb[t] = gn_b[t];
        sxs[t] = x_s[bg * CG + t];
    }
    for (int i = 0; i < 32; ++i) {
        sv[i][t] = (t < 64) ? x_h[(size_t)(bg * CG + i) * 64 + t]
                            : x_w[(size_t)(bg * CG + i) * 64 + (t - 64)];
    }
    __syncthreads();

    // conv1: y[o][p] = b1[o] + sum_i w1[o][i]*v[i][p]
    float vloc[32];
#pragma unroll
    for (int i = 0; i < 32; ++i) vloc[i] = sv[i][t];
    for (int o = 0; o < 32; ++o) {
        float acc = sb1[o];
#pragma unroll
        for (int i = 0; i < 32; ++i) acc += sw1[o][i] * vloc[i];
        sy[o][t] = acc;
    }
    __syncthreads();

    // GN stats per channel o over 128 positions
    {
        int o = t & 31, seg = t >> 5;
        float s = 0.f, ss = 0.f;
#pragma unroll
        for (int p = 0; p < 32; ++p) {
            float v = sy[o][seg * 32 + p];
            s += v; ss += v * v;
        }
        spart[0][seg][o] = s; spart[1][seg][o] = ss;
    }
    __syncthreads();
    if (t < 32) {
        float s  = spart[0][0][t] + spart[0][1][t] + spart[0][2][t] + spart[0][3][t];
        float ss = spart[1][0][t] + spart[1][1][t] + spart[1][2][t] + spart[1][3][t];
        float mu = s * (1.0f / 128.0f);
        float var = ss * (1.0f / 128.0f) - mu * mu;
        float rstd = rsqrtf(var + 1e-5f);
        float sc = rstd * sgg[t];
        sscale[t] = sc;
        sshift[t] = sgb[t] - mu * sc;
    }
    __syncthreads();

    // z[i] = h_swish(GN(y))[i][p]  (column p in registers)
    float z[32];
#pragma unroll
    for (int i = 0; i < 32; ++i) {
        float v = sy[i][t] * sscale[i] + sshift[i];
        float c = fminf(fmaxf(v + 3.0f, 0.0f), 6.0f);
        z[i] = v * c * (1.0f / 6.0f);
    }
    if (t < 64) {
        // a_h[o][h=t]
        for (int o = 0; o < 32; ++o) {
            float acc = sbh[o];
#pragma unroll
            for (int i = 0; i < 32; ++i) acc += swh[o][i] * z[i];
            a_h[(size_t)(bg * CG + o) * 64 + t] = acc;
        }
    } else {
        int wc = t - 64;
        // a_ws[o][w] = a_w[o][w] * x_s[o]
        for (int o = 0; o < 32; ++o) {
            float acc = sbw[o];
#pragma unroll
            for (int i = 0; i < 32; ++i) acc += sww[o][i] * z[i];
            a_ws[(size_t)(bg * CG + o) * 64 + wc] = acc * sxs[o];
        }
    }
}

// ---------------------------------------------------------------------------
// Kernel 3: elementwise gate + channel shuffle. One block per OUTPUT plane.
// final[n, 2j+k] = out[n, k*256+j]; out channel cc -> group g=cc/64, cgi=cc%64.
// ---------------------------------------------------------------------------
__global__ __launch_bounds__(256) void k_final(
    const float* __restrict__ x, const float* __restrict__ s_c,
    const float* __restrict__ a_h, const float* __restrict__ a_ws,
    float* __restrict__ out) {
    int bid = blockIdx.x;           // 0..16383
    int n  = bid >> 9;              // /512
    int cf = bid & 511;             // final channel
    int j = cf >> 1, k = cf & 1;
    int cc = k * 256 + j;
    int g = cc >> 6, cgi = cc & 63;
    int bg = n * 8 + g;
    const float4* src = (const float4*)(x   + (size_t)(n * 512 + g * 64 + cgi) * HW);
    float4*       dst = (float4*)      (out + (size_t)(n * 512 + cf) * HW);
    int t = threadIdx.x;

    __shared__ float sah[64], saw[64];

    if (cgi < CG) {
        // channel attention: uniform scale
        float sc = s_c[bg * CG + cgi];
#pragma unroll
        for (int q = 0; q < 4; ++q) {
            float4 v = src[q * 256 + t];
            v.x *= sc; v.y *= sc; v.z *= sc; v.w *= sc;
            dst[q * 256 + t] = v;
        }
    } else {
        int c1 = cgi - CG;
        if (t < 64)       sah[t]      = a_h [(size_t)(bg * CG + c1) * 64 + t];
        else if (t < 128) saw[t - 64] = a_ws[(size_t)(bg * CG + c1) * 64 + (t - 64)];
        __syncthreads();
#pragma unroll
        for (int q = 0; q < 4; ++q) {
            int vi = q * 256 + t;            // float4 index in plane
            float4 v = src[vi];
            int h  = vi >> 4;                // 4 floats/lane, 16 lanes/row
            int wb = (vi & 15) * 4;
            float ah = sah[h];
            v.x *= sigmoidf_(ah * saw[wb + 0]);
            v.y *= sigmoidf_(ah * saw[wb + 1]);
            v.z *= sigmoidf_(ah * saw[wb + 2]);
            v.w *= sigmoidf_(ah * saw[wb + 3]);
            dst[vi] = v;
        }
    }
}

// ---------------------------------------------------------------------------
extern "C" void kernel_launch(void* const* d_in, const int* in_sizes, int n_in,
                              void* d_out, int out_size, void* d_ws, size_t ws_size,
                              hipStream_t stream) {
    const float* x        = (const float*)d_in[0];
    const float* cweight  = (const float*)d_in[1];
    const float* cbias    = (const float*)d_in[2];
    const float* conv1_w  = (const float*)d_in[3];
    const float* conv1_b  = (const float*)d_in[4];
    const float* gn_g     = (const float*)d_in[5];
    const float* gn_b     = (const float*)d_in[6];
    const float* convh_w  = (const float*)d_in[7];
    const float* convh_b  = (const float*)d_in[8];
    const float* convw_w  = (const float*)d_in[9];
    const float* convw_b  = (const float*)d_in[10];
    float* out = (float*)d_out;

    // workspace layout (floats): ~8.5 MB total
    float* ws   = (float*)d_ws;
    float* s_c  = ws;                    // 256*32
    float* x_s  = s_c  + NBG * CG;       // 256*32
    float* x_h  = x_s  + NBG * CG;       // 256*32*64
    float* x_w  = x_h  + NBG * CG * 64;  // 256*32*64
    float* a_h  = x_w  + NBG * CG * 64;  // 256*32*64
    float* a_ws = a_h  + NBG * CG * 64;  // 256*32*64

    k_reduce<<<NBG * 64, 64, 0, stream>>>(x, cweight, cbias, s_c, x_s, x_h, x_w);
    k_mid<<<NBG, 128, 0, stream>>>(x_h, x_w, x_s,
                                   conv1_w, conv1_b, gn_g, gn_b,
                                   convh_w, convh_b, convw_w, convw_b,
                                   a_h, a_ws);
    k_final<<<NBG * 64, 256, 0, stream>>>(x, s_c, a_h, a_ws, out);
}

// Round 2
// 507.493 us; speedup vs baseline: 1.0199x; 1.0199x over previous
//
#include <hip/hip_runtime.h>
#include <hip/hip_bf16.h>
#include <math.h>

// SCSA: x(32,512,64,64) fp32 -> 256 "images" of 64ch x 64 x 64 (G=8).
//   ch 0-31 : channel attention  x * sigmoid(cw*gap + cb)   -> fused into k_reduce
//   ch 32-63: spatial attention  x * sigmoid(a_h[h]*a_w[w]*x_s) -> k_final
// Output channel shuffle: cc (concat order) -> cf = 2*(cc&255) + (cc>>8).

#define HW 4096      // 64*64
#define CG 32        // channels per half-group
#define NBG 256      // 32 batches * 8 groups

__device__ __forceinline__ float sigmoidf_(float t) {
    return 1.0f / (1.0f + __expf(-t));
}

// ---------------------------------------------------------------------------
// Kernel 1: plane reductions; 4 waves/block, one plane per wave.
// ch<32: also writes the channel-attention output plane (registers already
//        hold the data -> saves a 128 MiB re-read later).
// ch>=32: writes x_s (global mean), x_h (row means), x_w (col means).
// ---------------------------------------------------------------------------
__global__ __launch_bounds__(256) void k_reduce(
    const float* __restrict__ x,
    const float* __restrict__ cweight, const float* __restrict__ cbias,
    float* __restrict__ out,
    float* __restrict__ x_s, float* __restrict__ x_h, float* __restrict__ x_w) {
    int wid = threadIdx.x >> 6;      // wave in block 0..3
    int l   = threadIdx.x & 63;      // lane
    int gp  = blockIdx.x * 4 + wid;  // plane id 0..16383
    int bg  = gp >> 6;               // image 0..255
    int ch  = gp & 63;               // channel in image
    int n = bg >> 3, g = bg & 7;
    const float4* plane = (const float4*)(x + (size_t)(n * 512 + g * 64 + ch) * HW);

    __shared__ float part[4][64][17];   // per-wave row partials (pad 17: no conflicts)

    // lane l, iter i -> float4 of row (4i + l/16), cols 4*(l&15)..+3
    float4 v[16];
#pragma unroll
    for (int i = 0; i < 16; ++i) v[i] = plane[i * 64 + l];

    float cs0 = 0.f, cs1 = 0.f, cs2 = 0.f, cs3 = 0.f;
#pragma unroll
    for (int i = 0; i < 16; ++i) {
        cs0 += v[i].x; cs1 += v[i].y; cs2 += v[i].z; cs3 += v[i].w;
        part[wid][i * 4 + (l >> 4)][l & 15] = (v[i].x + v[i].y) + (v[i].z + v[i].w);
    }
    // column sums: lanes {l, l^16, l^32, l^48} cover same cols, different rows
    cs0 += __shfl_xor(cs0, 16); cs0 += __shfl_xor(cs0, 32);
    cs1 += __shfl_xor(cs1, 16); cs1 += __shfl_xor(cs1, 32);
    cs2 += __shfl_xor(cs2, 16); cs2 += __shfl_xor(cs2, 32);
    cs3 += __shfl_xor(cs3, 16); cs3 += __shfl_xor(cs3, 32);
    float tot = (cs0 + cs1) + (cs2 + cs3);
    tot += __shfl_xor(tot, 1);
    tot += __shfl_xor(tot, 2);
    tot += __shfl_xor(tot, 4);
    tot += __shfl_xor(tot, 8);        // full plane sum, all lanes

    __syncthreads();
    float rsum = 0.f;
#pragma unroll
    for (int j = 0; j < 16; ++j) rsum += part[wid][l][j];   // row l sum

    if (ch < CG) {
        // channel attention fused here: scale plane (still in regs) and store
        float sc = sigmoidf_(cweight[ch] * (tot * (1.0f / HW)) + cbias[ch]);
        int cc = g * 64 + ch;
        int cf = 2 * (cc & 255) + (cc >> 8);
        float4* dst = (float4*)(out + (size_t)(n * 512 + cf) * HW);
#pragma unroll
        for (int i = 0; i < 16; ++i) {
            float4 t = v[i];
            t.x *= sc; t.y *= sc; t.z *= sc; t.w *= sc;
            dst[i * 64 + l] = t;
        }
    } else {
        int c1 = ch - CG;
        if (l == 0) x_s[bg * CG + c1] = tot * (1.0f / HW);
        x_h[(size_t)(bg * CG + c1) * 64 + l] = rsum * (1.0f / 64.0f);
        if (l < 16) {
            float4 cw;
            cw.x = cs0 * (1.0f / 64.0f); cw.y = cs1 * (1.0f / 64.0f);
            cw.z = cs2 * (1.0f / 64.0f); cw.w = cs3 * (1.0f / 64.0f);
            ((float4*)(x_w + (size_t)(bg * CG + c1) * 64))[l] = cw;
        }
    }
}

// ---------------------------------------------------------------------------
// Kernel 2: per-image conv1 -> GN -> h-swish -> convh/convw. 256 blocks x 128.
// Thread t = position p (0-63: h, 64-127: w). Weights read with block-uniform
// indices straight from global -> compiler scalarizes to s_load (K$), keeping
// the vector/LDS pipes free.
// ---------------------------------------------------------------------------
__global__ __launch_bounds__(128) void k_mid(
    const float* __restrict__ x_h, const float* __restrict__ x_w,
    const float* __restrict__ x_s,
    const float* __restrict__ w1, const float* __restrict__ b1,
    const float* __restrict__ gn_g, const float* __restrict__ gn_b,
    const float* __restrict__ wh, const float* __restrict__ bh,
    const float* __restrict__ ww, const float* __restrict__ bw,
    float* __restrict__ a_h, float* __restrict__ a_ws) {
    int bg = blockIdx.x;
    int t  = threadIdx.x;

    __shared__ float sy[32][129];     // conv1 output (pad: conflict-free both ways)
    __shared__ float spart[2][4][32];
    __shared__ float sscale[32], sshift[32];

    // pooled features for position t, all 32 input channels (coalesced loads)
    float vloc[32];
#pragma unroll
    for (int i = 0; i < 32; ++i) {
        vloc[i] = (t < 64) ? x_h[(size_t)(bg * CG + i) * 64 + t]
                           : x_w[(size_t)(bg * CG + i) * 64 + (t - 64)];
    }

    // conv1: y[o][t] = b1[o] + sum_i w1[o][i]*v[i][t]   (w1 uniform -> s_load)
    for (int o = 0; o < 32; ++o) {
        float acc = b1[o];
#pragma unroll
        for (int i = 0; i < 32; ++i) acc += w1[o * 32 + i] * vloc[i];
        sy[o][t] = acc;
    }
    __syncthreads();

    // GN stats per channel o over 128 positions
    {
        int o = t & 31, seg = t >> 5;
        float s = 0.f, ss = 0.f;
#pragma unroll
        for (int p = 0; p < 32; ++p) {
            float v = sy[o][seg * 32 + p];
            s += v; ss += v * v;
        }
        spart[0][seg][o] = s; spart[1][seg][o] = ss;
    }
    __syncthreads();
    if (t < 32) {
        float s  = spart[0][0][t] + spart[0][1][t] + spart[0][2][t] + spart[0][3][t];
        float ss = spart[1][0][t] + spart[1][1][t] + spart[1][2][t] + spart[1][3][t];
        float mu = s * (1.0f / 128.0f);
        float var = ss * (1.0f / 128.0f) - mu * mu;
        float rstd = rsqrtf(var + 1e-5f);
        float sc = rstd * gn_g[t];
        sscale[t] = sc;
        sshift[t] = gn_b[t] - mu * sc;
    }
    __syncthreads();

    // z[i] = h_swish(GN(y))[i][t]
    float z[32];
#pragma unroll
    for (int i = 0; i < 32; ++i) {
        float v = sy[i][t] * sscale[i] + sshift[i];
        float c = fminf(fmaxf(v + 3.0f, 0.0f), 6.0f);
        z[i] = v * c * (1.0f / 6.0f);
    }
    if (t < 64) {
        for (int o = 0; o < 32; ++o) {
            float acc = bh[o];
#pragma unroll
            for (int i = 0; i < 32; ++i) acc += wh[o * 32 + i] * z[i];
            a_h[(size_t)(bg * CG + o) * 64 + t] = acc;
        }
    } else {
        int wc = t - 64;
        for (int o = 0; o < 32; ++o) {
            float acc = bw[o];
#pragma unroll
            for (int i = 0; i < 32; ++i) acc += ww[o * 32 + i] * z[i];
            a_ws[(size_t)(bg * CG + o) * 64 + wc] = acc * x_s[bg * CG + o];
        }
    }
}

// ---------------------------------------------------------------------------
// Kernel 3: spatial gate only (channel half already written by k_reduce).
// One block per spatial plane: 8192 blocks x 256.
// ---------------------------------------------------------------------------
__global__ __launch_bounds__(256) void k_final(
    const float* __restrict__ x,
    const float* __restrict__ a_h, const float* __restrict__ a_ws,
    float* __restrict__ out) {
    int bid = blockIdx.x;           // 0..8191
    int bg = bid >> 5;              // image 0..255
    int c1 = bid & 31;              // spatial channel 0..31
    int n = bg >> 3, g = bg & 7;
    int cc = g * 64 + 32 + c1;
    int cf = 2 * (cc & 255) + (cc >> 8);
    const float4* src = (const float4*)(x   + (size_t)(n * 512 + g * 64 + 32 + c1) * HW);
    float4*       dst = (float4*)      (out + (size_t)(n * 512 + cf) * HW);
    int t = threadIdx.x;

    __shared__ float sah[64], saw[64];
    if (t < 64)       sah[t]      = a_h [(size_t)(bg * CG + c1) * 64 + t];
    else if (t < 128) saw[t - 64] = a_ws[(size_t)(bg * CG + c1) * 64 + (t - 64)];
    __syncthreads();

#pragma unroll
    for (int q = 0; q < 4; ++q) {
        int vi = q * 256 + t;            // float4 index in plane
        float4 v = src[vi];
        int h  = vi >> 4;                // 16 float4 per row
        int wb = (vi & 15) * 4;
        float ah = sah[h];
        v.x *= sigmoidf_(ah * saw[wb + 0]);
        v.y *= sigmoidf_(ah * saw[wb + 1]);
        v.z *= sigmoidf_(ah * saw[wb + 2]);
        v.w *= sigmoidf_(ah * saw[wb + 3]);
        dst[vi] = v;
    }
}

// ---------------------------------------------------------------------------
extern "C" void kernel_launch(void* const* d_in, const int* in_sizes, int n_in,
                              void* d_out, int out_size, void* d_ws, size_t ws_size,
                              hipStream_t stream) {
    const float* x        = (const float*)d_in[0];
    const float* cweight  = (const float*)d_in[1];
    const float* cbias    = (const float*)d_in[2];
    const float* conv1_w  = (const float*)d_in[3];
    const float* conv1_b  = (const float*)d_in[4];
    const float* gn_g     = (const float*)d_in[5];
    const float* gn_b     = (const float*)d_in[6];
    const float* convh_w  = (const float*)d_in[7];
    const float* convh_b  = (const float*)d_in[8];
    const float* convw_w  = (const float*)d_in[9];
    const float* convw_b  = (const float*)d_in[10];
    float* out = (float*)d_out;

    // workspace (floats): x_s 8K, x_h/x_w/a_h/a_ws 512K each -> ~8.2 MB
    float* ws   = (float*)d_ws;
    float* x_s  = ws;
    float* x_h  = x_s + NBG * CG;
    float* x_w  = x_h + NBG * CG * 64;
    float* a_h  = x_w + NBG * CG * 64;
    float* a_ws = a_h + NBG * CG * 64;

    k_reduce<<<NBG * 64 / 4, 256, 0, stream>>>(x, cweight, cbias, out, x_s, x_h, x_w);
    k_mid<<<NBG, 128, 0, stream>>>(x_h, x_w, x_s,
                                   conv1_w, conv1_b, gn_g, gn_b,
                                   convh_w, convh_b, convw_w, convw_b,
                                   a_h, a_ws);
    k_final<<<NBG * CG, 256, 0, stream>>>(x, a_h, a_ws, out);
}